// Round 1
// baseline (642.336 us; speedup 1.0000x reference)
//
#include <hip/hip_runtime.h>
#include <float.h>
#include <math.h>

// CrossAtt: q = query@Wq^T, k = x@Wk^T, v = x@Wv^T
// att_w = masked softmax(q k^T), result = att_w @ v. Outputs: [result | att_w].
// fp32 everywhere (no fp32 MFMA on CDNA4 -> vector ALU GEMMs this round).

#define B  8
#define LQ 2048
#define LK 2048
#define D  128
#define NROWS (B*LQ)            // 16384

// ws layout in floats
#define Q_OFF  0
#define K_OFF  (NROWS*D)        // 2,097,152
#define V_OFF  (2*NROWS*D)
#define M2_OFF (3*NROWS*D)      // m[2][NROWS], z[2][NROWS]
#define P_OFF  (M2_OFF + 4*NROWS) // partial result [2][NROWS*D]

#define BQ 64
#define BK 64
#define QSTR 132   // padded stride for Q tile (64x128)
#define KSTR 68    // padded stride for K half-tile (64x64)
#define VSTR 132
#define WSTR 68

// ---------------- projection: dst[row][a] = sum_d src[row][d] * W[a][d] ----
__global__ __launch_bounds__(256) void proj_kernel(
    const float* __restrict__ query, const float* __restrict__ x,
    const float* __restrict__ Wq, const float* __restrict__ Wk,
    const float* __restrict__ Wv, float* __restrict__ ws)
{
  const int which = blockIdx.y;
  const float* __restrict__ src = (which == 0) ? query : x;
  const float* __restrict__ W   = (which == 0) ? Wq : (which == 1 ? Wk : Wv);
  float* __restrict__ dst = ws + (size_t)which * (NROWS * D);

  const int a    = threadIdx.x & 127;   // output column
  const int half = threadIdx.x >> 7;    // row parity (wave-uniform)

  // W row resident in VGPRs
  float w[D];
#pragma unroll
  for (int d = 0; d < D; d += 4) {
    float4 t4 = *(const float4*)&W[a * D + d];
    w[d] = t4.x; w[d + 1] = t4.y; w[d + 2] = t4.z; w[d + 3] = t4.w;
  }

  const int rbase = blockIdx.x * 64;
  for (int r = half; r < 64; r += 2) {
    const int row = rbase + r;
    const float* __restrict__ xr = src + (size_t)row * D;  // wave-uniform -> s_load
    float a0 = 0.f, a1 = 0.f, a2 = 0.f, a3 = 0.f;
#pragma unroll
    for (int d = 0; d < D; d += 4) {
      a0 = fmaf(xr[d],     w[d],     a0);
      a1 = fmaf(xr[d + 1], w[d + 1], a1);
      a2 = fmaf(xr[d + 2], w[d + 2], a2);
      a3 = fmaf(xr[d + 3], w[d + 3], a3);
    }
    dst[(size_t)row * D + a] = (a0 + a1) + (a2 + a3);
  }
}

// ---------------- scores: S = Q K^T (masked), online row max/sum ------------
// grid: (LQ/BQ, B, 2) -- z splits K range in halves of 1024
__global__ __launch_bounds__(256) void scores_kernel(
    const float* __restrict__ ws, const int* __restrict__ valid,
    float* __restrict__ att, float* __restrict__ wsm)
{
  __shared__ float Qs[BQ * QSTR];
  __shared__ float Ks[BK * KSTR];

  const int t  = threadIdx.x;
  const int bq = blockIdx.x;
  const int b  = blockIdx.y;
  const int kh = blockIdx.z;
  const int q0 = bq * BQ;
  const int tx = t & 15, ty = t >> 4;

  const float* __restrict__ Qg = ws + Q_OFF + ((size_t)(b * LQ + q0)) * D;
  const float* __restrict__ Kg = ws + K_OFF + ((size_t)b * LK) * D;

  // stage Q block (64 x 128) once
#pragma unroll
  for (int i = 0; i < 8; ++i) {
    int f = (t + i * 256) * 4;
    int r = f >> 7, d = f & 127;
    *(float4*)&Qs[r * QSTR + d] = *(const float4*)&Qg[(size_t)r * D + d];
  }

  float m_run[4], z_run[4];
#pragma unroll
  for (int i = 0; i < 4; ++i) { m_run[i] = -FLT_MAX; z_run[i] = 0.f; }

  for (int kt = 0; kt < 16; ++kt) {
    const int k0 = kh * 1024 + kt * BK;
    float s[4][4];
#pragma unroll
    for (int i = 0; i < 4; ++i)
#pragma unroll
      for (int j = 0; j < 4; ++j) s[i][j] = 0.f;

    for (int dh = 0; dh < 2; ++dh) {
      __syncthreads();
      // stage K half-tile (64 rows x 64 dims)
#pragma unroll
      for (int i = 0; i < 4; ++i) {
        int f = (t + i * 256) * 4;
        int r = f >> 6, dd = f & 63;
        *(float4*)&Ks[r * KSTR + dd] =
            *(const float4*)&Kg[(size_t)(k0 + r) * D + dh * 64 + dd];
      }
      __syncthreads();
#pragma unroll 4
      for (int dd = 0; dd < 64; dd += 4) {
        float4 qv[4], kv[4];
#pragma unroll
        for (int i = 0; i < 4; ++i)
          qv[i] = *(const float4*)&Qs[(ty * 4 + i) * QSTR + dh * 64 + dd];
#pragma unroll
        for (int j = 0; j < 4; ++j)
          kv[j] = *(const float4*)&Ks[(tx + 16 * j) * KSTR + dd];
#pragma unroll
        for (int i = 0; i < 4; ++i)
#pragma unroll
          for (int j = 0; j < 4; ++j) {
            s[i][j] = fmaf(qv[i].x, kv[j].x, s[i][j]);
            s[i][j] = fmaf(qv[i].y, kv[j].y, s[i][j]);
            s[i][j] = fmaf(qv[i].z, kv[j].z, s[i][j]);
            s[i][j] = fmaf(qv[i].w, kv[j].w, s[i][j]);
          }
      }
    }

    // mask -> store raw masked S, update online stats
#pragma unroll
    for (int i = 0; i < 4; ++i) {
      const int q = q0 + ty * 4 + i;
      const size_t base = ((size_t)(b * LQ + q)) * LK + k0 + tx;
      float sv[4];
      float tm = -FLT_MAX;
#pragma unroll
      for (int j = 0; j < 4; ++j) {
        int vld = valid[base + 16 * j];
        float v = (vld > 0) ? s[i][j] : -INFINITY;
        att[base + 16 * j] = v;
        sv[j] = v;
        tm = fmaxf(tm, v);
      }
#pragma unroll
      for (int o = 1; o < 16; o <<= 1) tm = fmaxf(tm, __shfl_xor(tm, o));
      const float mn = fmaxf(m_run[i], tm);
      const float sc = __expf(m_run[i] - mn);   // exp(0)=1 when unchanged / all-masked
      float zadd = 0.f;
#pragma unroll
      for (int j = 0; j < 4; ++j) zadd += __expf(sv[j] - mn); // masked -> exp(-inf)=0
      z_run[i] = z_run[i] * sc + zadd;
      m_run[i] = mn;
    }
  }

  // reduce z across the 16 tx lanes; write per-half stats
#pragma unroll
  for (int i = 0; i < 4; ++i) {
    float z = z_run[i];
#pragma unroll
    for (int o = 1; o < 16; o <<= 1) z += __shfl_xor(z, o);
    if (tx == 0) {
      const int q = b * LQ + q0 + ty * 4 + i;
      wsm[kh * NROWS + q] = m_run[i];            // m[kh][q]
      wsm[2 * NROWS + kh * NROWS + q] = z;       // z[kh][q]
    }
  }
}

// ---------------- pv: att_w = exp(S-m)/Z in-place; partial = att_w @ V ------
__global__ __launch_bounds__(256) void pv_kernel(
    const float* __restrict__ ws, float* __restrict__ att,
    float* __restrict__ part)
{
  __shared__ float Vs[BK * VSTR];
  __shared__ float Wt[BQ * WSTR];
  __shared__ float Ms[BQ], Zi[BQ];

  const int t  = threadIdx.x;
  const int bq = blockIdx.x, b = blockIdx.y, kh = blockIdx.z;
  const int q0 = bq * BQ;
  const int tx = t & 15, ty = t >> 4;

  const float* __restrict__ wsm = ws + M2_OFF;
  if (t < BQ) {
    const int q = b * LQ + q0 + t;
    float m0 = wsm[q],             m1 = wsm[NROWS + q];
    float z0 = wsm[2 * NROWS + q], z1 = wsm[3 * NROWS + q];
    float m = fmaxf(m0, m1);
    float z = z0 * __expf(m0 - m) + z1 * __expf(m1 - m);
    Ms[t] = m;
    Zi[t] = (z > 0.f) ? 1.f / z : 0.f;   // all-masked row -> 0
  }
  __syncthreads();

  const float* __restrict__ Vg = ws + V_OFF + ((size_t)b * LK) * D;

  float acc[4][8];
#pragma unroll
  for (int i = 0; i < 4; ++i)
#pragma unroll
    for (int j = 0; j < 8; ++j) acc[i][j] = 0.f;

  const int wrow = t >> 2;
  const int wcol = (t & 3) * 16;
  const float wm  = Ms[wrow];
  const float wzi = Zi[wrow];

  for (int kt = 0; kt < 16; ++kt) {
    const int k0 = kh * 1024 + kt * BK;
    __syncthreads();   // previous tile's LDS reads done
    // stage V tile (64 x 128)
#pragma unroll
    for (int i = 0; i < 8; ++i) {
      int f = (t + i * 256) * 4;
      int r = f >> 7, d = f & 127;
      *(float4*)&Vs[r * VSTR + d] = *(const float4*)&Vg[(size_t)(k0 + r) * D + d];
    }
    // renormalize S -> att_w (in place) and stage w tile
    const size_t abase = ((size_t)(b * LQ + q0 + wrow)) * LK + k0 + wcol;
#pragma unroll
    for (int c = 0; c < 4; ++c) {
      float4 s4 = *(const float4*)&att[abase + c * 4];
      float4 w4;
      w4.x = __expf(s4.x - wm) * wzi;
      w4.y = __expf(s4.y - wm) * wzi;
      w4.z = __expf(s4.z - wm) * wzi;
      w4.w = __expf(s4.w - wm) * wzi;
      *(float4*)&att[abase + c * 4] = w4;
      *(float4*)&Wt[wrow * WSTR + wcol + c * 4] = w4;
    }
    __syncthreads();
    // GEMM: acc[q][d] += w[q][kk] * V[kk][d]
#pragma unroll 4
    for (int kk = 0; kk < BK; ++kk) {
      float wv[4];
#pragma unroll
      for (int i = 0; i < 4; ++i) wv[i] = Wt[(ty * 4 + i) * WSTR + kk];
#pragma unroll
      for (int j = 0; j < 4; ++j) {
        float2 v2 = *(const float2*)&Vs[kk * VSTR + 2 * tx + 32 * j];
#pragma unroll
        for (int i = 0; i < 4; ++i) {
          acc[i][2 * j]     = fmaf(wv[i], v2.x, acc[i][2 * j]);
          acc[i][2 * j + 1] = fmaf(wv[i], v2.y, acc[i][2 * j + 1]);
        }
      }
    }
  }

  float* __restrict__ P = part + (size_t)kh * (NROWS * D);
#pragma unroll
  for (int i = 0; i < 4; ++i) {
    const size_t rb = ((size_t)(b * LQ + q0 + ty * 4 + i)) * D;
#pragma unroll
    for (int j = 0; j < 4; ++j) {
      float2 o2 = make_float2(acc[i][2 * j], acc[i][2 * j + 1]);
      *(float2*)&P[rb + 2 * tx + 32 * j] = o2;
    }
  }
}

// ---------------- combine the two k-split partials --------------------------
__global__ __launch_bounds__(256) void combine_kernel(
    const float* __restrict__ part, float* __restrict__ out)
{
  const size_t idx = ((size_t)blockIdx.x * 256 + threadIdx.x) * 4;
  float4 p0 = *(const float4*)&part[idx];
  float4 p1 = *(const float4*)&part[(size_t)NROWS * D + idx];
  float4 r;
  r.x = p0.x + p1.x; r.y = p0.y + p1.y; r.z = p0.z + p1.z; r.w = p0.w + p1.w;
  *(float4*)&out[idx] = r;
}

extern "C" void kernel_launch(void* const* d_in, const int* in_sizes, int n_in,
                              void* d_out, int out_size, void* d_ws, size_t ws_size,
                              hipStream_t stream)
{
  (void)in_sizes; (void)n_in; (void)out_size; (void)ws_size;
  const float* query = (const float*)d_in[0];
  const float* x     = (const float*)d_in[1];
  const int*   valid = (const int*)d_in[2];
  const float* Wq    = (const float*)d_in[3];
  const float* Wk    = (const float*)d_in[4];
  const float* Wv    = (const float*)d_in[5];

  float* out = (float*)d_out;
  float* res = out;                         // [B][LQ][D]
  float* att = out + (size_t)NROWS * D;     // [B][LQ][LK]
  float* ws  = (float*)d_ws;                // needs ~42.2 MB

  proj_kernel<<<dim3(NROWS / 64, 3), 256, 0, stream>>>(query, x, Wq, Wk, Wv, ws);
  scores_kernel<<<dim3(LQ / BQ, B, 2), 256, 0, stream>>>(ws, valid, att, ws + M2_OFF);
  pv_kernel<<<dim3(LQ / BQ, B, 2), 256, 0, stream>>>(ws, att, ws + P_OFF);
  combine_kernel<<<dim3((NROWS * D / 4) / 256), 256, 0, stream>>>(ws + P_OFF, res);
}

// Round 2
// 523.101 us; speedup vs baseline: 1.2279x; 1.2279x over previous
//
#include <hip/hip_runtime.h>
#include <float.h>
#include <math.h>

// CrossAtt via bf16 hi/lo split MFMA (3-term: hh+hl+lh ~ fp32 accuracy).
// proj -> Qh/Ql,Kh/Kl (row-major bf16) + Vt hi/lo (transposed) in ws.
// scores: S = QK^T (MFMA), mask, write raw S to att region, per-row m,z partials.
// pv: w = exp(S-m)*zinv written to att_w, PV GEMM (MFMA) -> partials.
// combine: sum 2 k-split partials -> result.

#define BB 8
#define LQ 2048
#define LK 2048
#define DD 128
#define NROWS (BB*LQ)
#define KS 4     // scores k-split (k-range 512 each)
#define KSPV 2   // pv k-split    (k-range 1024 each)

typedef __attribute__((ext_vector_type(8))) short short8;
typedef __attribute__((ext_vector_type(4))) float f32x4;

// ws byte offsets
#define QH_OFF  (0)
#define QL_OFF  (1u*NROWS*DD*2u)
#define KH_OFF  (2u*NROWS*DD*2u)
#define KL_OFF  (3u*NROWS*DD*2u)
#define VTH_OFF (4u*NROWS*DD*2u)
#define VTL_OFF (5u*NROWS*DD*2u)
#define M_OFF   (6u*NROWS*DD*2u)            // [KS][NROWS] f32
#define Z_OFF   (M_OFF + KS*NROWS*4u)       // [KS][NROWS] f32
#define PART_OFF (0u)  // pv partials alias Q/K region (dead by then): [KSPV][NROWS*DD] f32

__device__ __forceinline__ f32x4 mfma16(short8 a, short8 b, f32x4 c) {
  return __builtin_amdgcn_mfma_f32_16x16x32_bf16(a, b, c, 0, 0, 0);
}
__device__ __forceinline__ unsigned short bfh(float v) {
  unsigned u = __float_as_uint(v);
  return (unsigned short)((u + 0x7FFFu + ((u >> 16) & 1u)) >> 16);
}
__device__ __forceinline__ float bff(unsigned short h) {
  return __uint_as_float(((unsigned)h) << 16);
}

// ---------------- proj: out = src @ W^T, split hi/lo; V transposed ----------
__global__ __launch_bounds__(256) void proj_kernel(
    const float* __restrict__ query, const float* __restrict__ x,
    const float* __restrict__ Wq, const float* __restrict__ Wk,
    const float* __restrict__ Wv, unsigned char* __restrict__ wsb)
{
  __shared__ unsigned short TH[DD][68];
  __shared__ unsigned short TL[DD][68];
  const int which = blockIdx.y;
  const float* __restrict__ src = (which == 0) ? query : x;
  const float* __restrict__ W   = (which == 0) ? Wq : (which == 1 ? Wk : Wv);
  const int t = threadIdx.x, l = t & 63, wv = t >> 6;
  const int lr = l & 15, lg = l >> 4;
  const int r0 = blockIdx.x * 64;
  const int row = r0 + wv * 16 + lr;

  // A-frags: src rows, hi/lo
  short8 ah[4], al[4];
#pragma unroll
  for (int dc = 0; dc < 4; ++dc) {
    const float* p = src + (size_t)row * DD + dc * 32 + lg * 8;
    float4 f0 = *(const float4*)p;
    float4 f1 = *(const float4*)(p + 4);
    float f[8] = {f0.x, f0.y, f0.z, f0.w, f1.x, f1.y, f1.z, f1.w};
    short8 h, lo;
#pragma unroll
    for (int e = 0; e < 8; ++e) {
      unsigned short hb = bfh(f[e]);
      h[e] = (short)hb; lo[e] = (short)bfh(f[e] - bff(hb));
    }
    ah[dc] = h; al[dc] = lo;
  }

  f32x4 acc[8];
#pragma unroll
  for (int a = 0; a < 8; ++a) acc[a] = (f32x4){0.f, 0.f, 0.f, 0.f};

#pragma unroll
  for (int dc = 0; dc < 4; ++dc) {
#pragma unroll
    for (int a = 0; a < 8; ++a) {
      const float* p = W + (size_t)(a * 16 + lr) * DD + dc * 32 + lg * 8;
      float4 f0 = *(const float4*)p;
      float4 f1 = *(const float4*)(p + 4);
      float f[8] = {f0.x, f0.y, f0.z, f0.w, f1.x, f1.y, f1.z, f1.w};
      short8 bh, bl;
#pragma unroll
      for (int e = 0; e < 8; ++e) {
        unsigned short hb = bfh(f[e]);
        bh[e] = (short)hb; bl[e] = (short)bfh(f[e] - bff(hb));
      }
      acc[a] = mfma16(ah[dc], bh, acc[a]);
      acc[a] = mfma16(ah[dc], bl, acc[a]);
      acc[a] = mfma16(al[dc], bh, acc[a]);
    }
  }

  if (which < 2) {
    unsigned short* Oh = (unsigned short*)(wsb + (which == 0 ? QH_OFF : KH_OFF));
    unsigned short* Ol = (unsigned short*)(wsb + (which == 0 ? QL_OFF : KL_OFF));
#pragma unroll
    for (int a = 0; a < 8; ++a)
#pragma unroll
      for (int i = 0; i < 4; ++i) {
        const int ro = r0 + wv * 16 + lg * 4 + i;
        const int co = a * 16 + lr;
        float v = acc[a][i];
        unsigned short h = bfh(v);
        Oh[(size_t)ro * DD + co] = h;
        Ol[(size_t)ro * DD + co] = bfh(v - bff(h));
      }
  } else {
    // V: transpose through LDS, store Vt[b][d][k]
#pragma unroll
    for (int a = 0; a < 8; ++a)
#pragma unroll
      for (int i = 0; i < 4; ++i) {
        const int rl = wv * 16 + lg * 4 + i;   // local k 0..63
        const int co = a * 16 + lr;            // d
        float v = acc[a][i];
        unsigned short h = bfh(v);
        TH[co][rl] = h;
        TL[co][rl] = bfh(v - bff(h));
      }
    __syncthreads();
    unsigned short* Vh = (unsigned short*)(wsb + VTH_OFF);
    unsigned short* Vl = (unsigned short*)(wsb + VTL_OFF);
    const int b = r0 >> 11, kloc = r0 & 2047;
    const int d = t >> 1, half = t & 1;
    const size_t gb = ((size_t)(b * DD + d)) * LK + kloc + half * 32;
#pragma unroll
    for (int j = 0; j < 8; ++j) {
      *(ushort4*)(Vh + gb + j * 4) = *(const ushort4*)&TH[d][half * 32 + j * 4];
      *(ushort4*)(Vl + gb + j * 4) = *(const ushort4*)&TL[d][half * 32 + j * 4];
    }
  }
}

// ---------------- scores ----------------------------------------------------
__global__ __launch_bounds__(256) void scores_kernel(
    const unsigned char* __restrict__ wsb, const int* __restrict__ valid,
    float* __restrict__ att)
{
  const int t = threadIdx.x, l = t & 63, wv = t >> 6;
  const int lr = l & 15, lg = l >> 4;
  const int qt = blockIdx.x, b = blockIdx.y, ks = blockIdx.z;
  const int q0 = qt * 128 + wv * 32;
  const unsigned short* Qh = (const unsigned short*)(wsb + QH_OFF);
  const unsigned short* Ql = (const unsigned short*)(wsb + QL_OFF);
  const unsigned short* Kh = (const unsigned short*)(wsb + KH_OFF);
  const unsigned short* Kl = (const unsigned short*)(wsb + KL_OFF);
  float* M = (float*)(wsb + M_OFF);
  float* Z = (float*)(wsb + Z_OFF);

  short8 qh[2][4], ql[2][4];
#pragma unroll
  for (int s = 0; s < 2; ++s)
#pragma unroll
    for (int dc = 0; dc < 4; ++dc) {
      const size_t idx = ((size_t)(b * LQ + q0 + s * 16 + lr)) * DD + dc * 32 + lg * 8;
      qh[s][dc] = *(const short8*)(Qh + idx);
      ql[s][dc] = *(const short8*)(Ql + idx);
    }

  float m_run[2][4], z_run[2][4];
#pragma unroll
  for (int s = 0; s < 2; ++s)
#pragma unroll
    for (int i = 0; i < 4; ++i) { m_run[s][i] = -FLT_MAX; z_run[s][i] = 0.f; }

  for (int kt = 0; kt < 8; ++kt) {
    const int k0 = ks * 512 + kt * 64;
    int vld[2][4][4];
#pragma unroll
    for (int s = 0; s < 2; ++s)
#pragma unroll
      for (int i = 0; i < 4; ++i) {
        const int* vp = valid + ((size_t)(b * LQ + q0 + s * 16 + lg * 4 + i)) * LK + k0 + lr;
#pragma unroll
        for (int kg = 0; kg < 4; ++kg) vld[s][kg][i] = vp[kg * 16];
      }

    f32x4 acc[2][4];
#pragma unroll
    for (int s = 0; s < 2; ++s)
#pragma unroll
      for (int kg = 0; kg < 4; ++kg) acc[s][kg] = (f32x4){0.f, 0.f, 0.f, 0.f};

#pragma unroll
    for (int kg = 0; kg < 4; ++kg)
#pragma unroll
      for (int dc = 0; dc < 4; ++dc) {
        const size_t kidx = ((size_t)(b * LK + k0 + kg * 16 + lr)) * DD + dc * 32 + lg * 8;
        short8 bh = *(const short8*)(Kh + kidx);
        short8 bl = *(const short8*)(Kl + kidx);
        acc[0][kg] = mfma16(qh[0][dc], bh, acc[0][kg]);
        acc[0][kg] = mfma16(ql[0][dc], bh, acc[0][kg]);
        acc[0][kg] = mfma16(qh[0][dc], bl, acc[0][kg]);
        acc[1][kg] = mfma16(qh[1][dc], bh, acc[1][kg]);
        acc[1][kg] = mfma16(ql[1][dc], bh, acc[1][kg]);
        acc[1][kg] = mfma16(qh[1][dc], bl, acc[1][kg]);
      }

#pragma unroll
    for (int s = 0; s < 2; ++s) {
      float sv[4][4];
#pragma unroll
      for (int i = 0; i < 4; ++i) {
        float* ap = att + ((size_t)(b * LQ + q0 + s * 16 + lg * 4 + i)) * LK + k0 + lr;
#pragma unroll
        for (int kg = 0; kg < 4; ++kg) {
          float v = (vld[s][kg][i] > 0) ? acc[s][kg][i] : -INFINITY;
          sv[kg][i] = v;
          ap[kg * 16] = v;
        }
      }
#pragma unroll
      for (int i = 0; i < 4; ++i) {
        float tm = fmaxf(fmaxf(sv[0][i], sv[1][i]), fmaxf(sv[2][i], sv[3][i]));
#pragma unroll
        for (int o = 1; o < 16; o <<= 1) tm = fmaxf(tm, __shfl_xor(tm, o));
        const float mo = m_run[s][i];
        const float mn = fmaxf(mo, tm);
        float za = __expf(sv[0][i] - mn) + __expf(sv[1][i] - mn) +
                   __expf(sv[2][i] - mn) + __expf(sv[3][i] - mn);
#pragma unroll
        for (int o = 1; o < 16; o <<= 1) za += __shfl_xor(za, o);
        z_run[s][i] = z_run[s][i] * __expf(mo - mn) + za;
        m_run[s][i] = mn;
      }
    }
  }

  if (lr == 0) {
#pragma unroll
    for (int s = 0; s < 2; ++s)
#pragma unroll
      for (int i = 0; i < 4; ++i) {
        const size_t row = (size_t)(b * LQ + q0 + s * 16 + lg * 4 + i);
        M[(size_t)ks * NROWS + row] = m_run[s][i];
        Z[(size_t)ks * NROWS + row] = z_run[s][i];
      }
  }
}

// ---------------- pv --------------------------------------------------------
__global__ __launch_bounds__(256) void pv_kernel(
    const unsigned char* __restrict__ wsb, float* __restrict__ att,
    float* __restrict__ part)
{
  const int t = threadIdx.x, l = t & 63, wv = t >> 6;
  const int lr = l & 15, lg = l >> 4;
  const int qt = blockIdx.x, b = blockIdx.y, kp = blockIdx.z;
  const int q0 = qt * 128 + wv * 32;
  const unsigned short* Vh = (const unsigned short*)(wsb + VTH_OFF);
  const unsigned short* Vl = (const unsigned short*)(wsb + VTL_OFF);
  const float* M = (const float*)(wsb + M_OFF);
  const float* Z = (const float*)(wsb + Z_OFF);

  float mf[2], zi[2];
#pragma unroll
  for (int s = 0; s < 2; ++s) {
    const size_t row = (size_t)(b * LQ + q0 + s * 16 + lr);
    float m0 = M[row], m1 = M[NROWS + row], m2 = M[2 * NROWS + row], m3 = M[3 * NROWS + row];
    float m = fmaxf(fmaxf(m0, m1), fmaxf(m2, m3));
    float z = Z[row] * __expf(m0 - m) + Z[NROWS + row] * __expf(m1 - m) +
              Z[2 * NROWS + row] * __expf(m2 - m) + Z[3 * NROWS + row] * __expf(m3 - m);
    mf[s] = m;
    zi[s] = (z > 0.f) ? 1.f / z : 0.f;
  }

  f32x4 acc[2][8];
#pragma unroll
  for (int s = 0; s < 2; ++s)
#pragma unroll
    for (int df = 0; df < 8; ++df) acc[s][df] = (f32x4){0.f, 0.f, 0.f, 0.f};

  for (int kt = 0; kt < 16; ++kt) {
    const int k0 = kp * 1024 + kt * 64;
    short8 wh[2][2], wl[2][2];
#pragma unroll
    for (int s = 0; s < 2; ++s)
#pragma unroll
      for (int kc = 0; kc < 2; ++kc) {
        float* p = att + ((size_t)(b * LQ + q0 + s * 16 + lr)) * LK + k0 + kc * 32 + lg * 8;
        float4 f0 = *(const float4*)p;
        float4 f1 = *(const float4*)(p + 4);
        float f[8] = {f0.x, f0.y, f0.z, f0.w, f1.x, f1.y, f1.z, f1.w};
        short8 h, lo;
#pragma unroll
        for (int e = 0; e < 8; ++e) {
          float w = __expf(f[e] - mf[s]) * zi[s];
          f[e] = w;
          unsigned short hb = bfh(w);
          h[e] = (short)hb; lo[e] = (short)bfh(w - bff(hb));
        }
        *(float4*)p       = (float4){f[0], f[1], f[2], f[3]};
        *(float4*)(p + 4) = (float4){f[4], f[5], f[6], f[7]};
        wh[s][kc] = h; wl[s][kc] = lo;
      }
#pragma unroll
    for (int kc = 0; kc < 2; ++kc)
#pragma unroll
      for (int df = 0; df < 8; ++df) {
        const size_t vidx = ((size_t)(b * DD + df * 16 + lr)) * LK + k0 + kc * 32 + lg * 8;
        short8 vh = *(const short8*)(Vh + vidx);
        short8 vl = *(const short8*)(Vl + vidx);
#pragma unroll
        for (int s = 0; s < 2; ++s) {
          acc[s][df] = mfma16(wh[s][kc], vh, acc[s][df]);
          acc[s][df] = mfma16(wh[s][kc], vl, acc[s][df]);
          acc[s][df] = mfma16(wl[s][kc], vh, acc[s][df]);
        }
      }
  }

  float* P = part + (size_t)kp * NROWS * DD;
#pragma unroll
  for (int s = 0; s < 2; ++s)
#pragma unroll
    for (int df = 0; df < 8; ++df)
#pragma unroll
      for (int i = 0; i < 4; ++i)
        P[((size_t)(b * LQ + q0 + s * 16 + lg * 4 + i)) * DD + df * 16 + lr] = acc[s][df][i];
}

// ---------------- combine ---------------------------------------------------
__global__ __launch_bounds__(256) void combine_kernel(
    const float* __restrict__ part, float* __restrict__ out)
{
  const size_t i = ((size_t)blockIdx.x * 256 + threadIdx.x) * 4;
  float4 a = *(const float4*)(part + i);
  float4 c = *(const float4*)(part + (size_t)NROWS * DD + i);
  *(float4*)(out + i) = (float4){a.x + c.x, a.y + c.y, a.z + c.z, a.w + c.w};
}

extern "C" void kernel_launch(void* const* d_in, const int* in_sizes, int n_in,
                              void* d_out, int out_size, void* d_ws, size_t ws_size,
                              hipStream_t stream)
{
  (void)in_sizes; (void)n_in; (void)out_size; (void)ws_size;
  const float* query = (const float*)d_in[0];
  const float* x     = (const float*)d_in[1];
  const int*   valid = (const int*)d_in[2];
  const float* Wq    = (const float*)d_in[3];
  const float* Wk    = (const float*)d_in[4];
  const float* Wv    = (const float*)d_in[5];

  float* out = (float*)d_out;
  float* res = out;                          // [B][LQ][D]
  float* att = out + (size_t)NROWS * DD;     // [B][LQ][LK]
  unsigned char* wsb = (unsigned char*)d_ws; // ~25.7 MB used

  proj_kernel<<<dim3(NROWS / 64, 3), 256, 0, stream>>>(query, x, Wq, Wk, Wv, wsb);
  scores_kernel<<<dim3(LQ / 128, BB, KS), 256, 0, stream>>>(wsb, valid, att);
  pv_kernel<<<dim3(LQ / 128, BB, KSPV), 256, 0, stream>>>(wsb, att, (float*)(wsb + PART_OFF));
  combine_kernel<<<dim3((NROWS * DD / 4) / 256), 256, 0, stream>>>((const float*)(wsb + PART_OFF), res);
}